// Round 1
// baseline (1459.467 us; speedup 1.0000x reference)
//
#include <hip/hip_runtime.h>

// HeteroGAT: 2-layer bipartite GAT (heads=4,ch=25 concat + edge feat; then heads=1,ch=100).
// Structure: CSR-by-dst build -> 4x GEMM+att fuse -> wave-per-dst-node gather (layer1, elu)
//            -> 4x GEMM+att -> wave-per-dst-node gather (layer2) -> d_out.

#define NNODES 50000
#define NEDGES 800000

// ---------------- ce[h] = sum_c We[h*25+c]*ae[h*25+c] (edge-attn constant) ----------------
__global__ void ce_kernel(const float* __restrict__ WeA, const float* __restrict__ aeA,
                          const float* __restrict__ WeB, const float* __restrict__ aeB,
                          float* __restrict__ ce /*[8]: 0..3=AB, 4..7=BA*/) {
    const float* We = blockIdx.x ? WeB : WeA;
    const float* ae = blockIdx.x ? aeB : aeA;
    __shared__ float s[4];
    int tid = threadIdx.x;
    if (tid < 4) s[tid] = 0.f;
    __syncthreads();
    if (tid < 100) atomicAdd(&s[tid / 25], We[tid] * ae[tid]);
    __syncthreads();
    if (tid < 4) ce[blockIdx.x * 4 + tid] = s[tid];
}

// ---------------- CSR build ----------------
__global__ void count_kernel(const int* __restrict__ eiA, const int* __restrict__ eiB,
                             int E, int* cntA, int* cntB) {
    int i = blockIdx.x * blockDim.x + threadIdx.x;
    if (i < E) atomicAdd(&cntA[eiA[E + i]], 1);
    else if (i < 2 * E) atomicAdd(&cntB[eiB[E + (i - E)]], 1);
}

__global__ __launch_bounds__(1024) void scan_kernel(
    const int* __restrict__ cntA, const int* __restrict__ cntB,
    int* __restrict__ roA, int* __restrict__ roB,
    int* __restrict__ curA, int* __restrict__ curB, int N) {
    const int* cnt = blockIdx.x ? cntB : cntA;
    int* ro  = blockIdx.x ? roB : roA;
    int* cur = blockIdx.x ? curB : curA;
    const int T = 1024;
    int tid = threadIdx.x;
    int chunk = (N + T - 1) / T;
    int lo = tid * chunk;
    int hi = lo + chunk; if (hi > N) hi = N; if (lo > N) lo = N;
    int sum = 0;
    for (int i = lo; i < hi; ++i) sum += cnt[i];
    __shared__ int part[1024];
    part[tid] = sum;
    __syncthreads();
    for (int off = 1; off < T; off <<= 1) {
        int t = (tid >= off) ? part[tid - off] : 0;
        __syncthreads();
        part[tid] += t;
        __syncthreads();
    }
    int run = (tid == 0) ? 0 : part[tid - 1];
    for (int i = lo; i < hi; ++i) {
        int c = cnt[i];
        cur[i] = run;
        run += c;
        ro[i + 1] = run;
    }
    if (tid == 0) ro[0] = 0;
}

__global__ void fill_kernel(const int* __restrict__ eiA, const int* __restrict__ eiB,
                            const float* __restrict__ wA, const float* __restrict__ wB,
                            int E, int* curA, int* curB,
                            int* __restrict__ ssA, int* __restrict__ ssB,
                            float* __restrict__ swA, float* __restrict__ swB) {
    int i = blockIdx.x * blockDim.x + threadIdx.x;
    if (i < E) {
        int s = eiA[i], d = eiA[E + i];
        int pos = atomicAdd(&curA[d], 1);
        ssA[pos] = s; swA[pos] = wA[i];
    } else if (i < 2 * E) {
        int j = i - E;
        int s = eiB[j], d = eiB[E + j];
        int pos = atomicAdd(&curB[d], 1);
        ssB[pos] = s; swB[pos] = wB[j];
    }
}

// ---------------- GEMM [N,K]x[K,100] + fused att[n,h] = sum_c H[n,h*ch+c]*a[h*ch+c] ----------------
// 128 threads: lane c = output col (100 active). 16 nodes/block staged as float4 in LDS
// (reads are wave-uniform broadcasts -> conflict-free). W k-tile held in VGPRs.
template <int K, int HEADS>
__global__ __launch_bounds__(128) void gemm_att_kernel(
    const float* __restrict__ X, const float* __restrict__ W,
    const float* __restrict__ avec, float* __restrict__ H,
    float* __restrict__ att, int N) {
    constexpr int NB = 16;
    constexpr int KT = (K % 20 == 0) ? 20 : 16;
    static_assert(K % KT == 0, "K tiling");
    __shared__ float4 Xs[NB][K / 4];
    __shared__ float att_s[NB * HEADS];
    const int tid = threadIdx.x;
    const int node0 = blockIdx.x * NB;  // N is a multiple of 16 (50000)
    const float4* Xg = (const float4*)(X + (size_t)node0 * K);
    for (int i = tid; i < NB * (K / 4); i += 128) ((float4*)Xs)[i] = Xg[i];
    if (tid < NB * HEADS) att_s[tid] = 0.f;
    __syncthreads();
    const int c = tid;
    float acc[NB];
#pragma unroll
    for (int i = 0; i < NB; ++i) acc[i] = 0.f;
    if (c < 100) {
        for (int kt = 0; kt < K; kt += KT) {
            float wr[KT];
#pragma unroll
            for (int j = 0; j < KT; ++j) wr[j] = W[(kt + j) * 100 + c];
#pragma unroll
            for (int i = 0; i < NB; ++i) {
#pragma unroll
                for (int q = 0; q < KT / 4; ++q) {
                    float4 xv = Xs[i][kt / 4 + q];
                    acc[i] = fmaf(xv.x, wr[4 * q + 0], acc[i]);
                    acc[i] = fmaf(xv.y, wr[4 * q + 1], acc[i]);
                    acc[i] = fmaf(xv.z, wr[4 * q + 2], acc[i]);
                    acc[i] = fmaf(xv.w, wr[4 * q + 3], acc[i]);
                }
            }
        }
        const float av = avec[c];
        const int h = c / (100 / HEADS);
#pragma unroll
        for (int i = 0; i < NB; ++i) {
            H[(size_t)(node0 + i) * 100 + c] = acc[i];
            atomicAdd(&att_s[i * HEADS + h], acc[i] * av);
        }
    }
    __syncthreads();
    if (tid < NB * HEADS) att[(size_t)node0 * HEADS + tid] = att_s[tid];
}

// ---------------- layer-1 gather: wave per dst node, heads=4, ch=25, edge weight, elu ----------------
// lane handles channels c0=lane, c1=64+lane (if <100). Softmax denom accumulated per lane
// (identical within a head group), so no cross-lane reduction and no float atomics.
__global__ __launch_bounds__(256) void gather4_kernel(
    const int* __restrict__ row_off, const int* __restrict__ ssrc,
    const float* __restrict__ sw, const float* __restrict__ hs /*[Ns,100]*/,
    const float* __restrict__ as_ /*[Ns,4]*/, const float* __restrict__ ad /*[Nd,4]*/,
    const float* __restrict__ ce /*[4]*/, const float* __restrict__ bias /*[100]*/,
    float* __restrict__ outp /*[Nd,100]*/, int Nd) {
    int wid = (int)((blockIdx.x * blockDim.x + threadIdx.x) >> 6);
    if (wid >= Nd) return;
    const int n = __builtin_amdgcn_readfirstlane(wid);
    const int lane = threadIdx.x & 63;
    const int beg = row_off[n], end = row_off[n + 1];
    const int c0 = lane, c1 = 64 + lane;
    const bool has1 = (c1 < 100);
    const int h0 = c0 / 25;
    const int h1 = (c1 / 25) & 3;  // valid head when has1; masked to stay in-bounds otherwise
    const float ce0 = ce[h0], ce1 = ce[h1];
    const float ad0 = ad[n * 4 + h0], ad1 = ad[n * 4 + h1];
    float acc0 = 0.f, acc1 = 0.f, d0 = 0.f, d1 = 0.f;
    for (int p = beg; p < end; ++p) {
        const int s = ssrc[p];
        const float w = sw[p];
        const float* asrow = as_ + (size_t)s * 4;
        float l0 = asrow[h0] + ad0 + w * ce0;
        float l1 = asrow[h1] + ad1 + w * ce1;
        l0 = fmaxf(l0, 0.2f * l0);  // leaky_relu(0.2)
        l1 = fmaxf(l1, 0.2f * l1);
        const float p0 = __expf(l0);
        const float p1 = __expf(l1);
        const float* hrow = hs + (size_t)s * 100;
        const float v0 = hrow[c0];
        const float v1 = has1 ? hrow[c1] : 0.f;
        acc0 = fmaf(p0, v0, acc0);
        acc1 = fmaf(p1, v1, acc1);
        d0 += p0;
        d1 += p1;
    }
    float r0 = (end > beg) ? acc0 / d0 : 0.f;
    float r1 = (end > beg) ? acc1 / d1 : 0.f;
    r0 += bias[c0];
    r0 = (r0 > 0.f) ? r0 : (__expf(r0) - 1.f);  // elu
    outp[(size_t)n * 100 + c0] = r0;
    if (has1) {
        r1 += bias[c1];
        r1 = (r1 > 0.f) ? r1 : (__expf(r1) - 1.f);
        outp[(size_t)n * 100 + c1] = r1;
    }
}

// ---------------- layer-2 gather: wave per dst node, heads=1, ch=100, no edge feat, no elu ----------------
__global__ __launch_bounds__(256) void gather1_kernel(
    const int* __restrict__ row_off, const int* __restrict__ ssrc,
    const float* __restrict__ hs /*[Ns,100]*/, const float* __restrict__ as_ /*[Ns]*/,
    const float* __restrict__ ad /*[Nd]*/, const float* __restrict__ bias /*[100]*/,
    float* __restrict__ outp /*[Nd,100]*/, int Nd) {
    int wid = (int)((blockIdx.x * blockDim.x + threadIdx.x) >> 6);
    if (wid >= Nd) return;
    const int n = __builtin_amdgcn_readfirstlane(wid);
    const int lane = threadIdx.x & 63;
    const int beg = row_off[n], end = row_off[n + 1];
    const int c0 = lane, c1 = 64 + lane;
    const bool has1 = (c1 < 100);
    const float adn = ad[n];
    float acc0 = 0.f, acc1 = 0.f, d0 = 0.f;
    for (int p = beg; p < end; ++p) {
        const int s = ssrc[p];
        float l = as_[s] + adn;
        l = fmaxf(l, 0.2f * l);
        const float pe = __expf(l);
        const float* hrow = hs + (size_t)s * 100;
        const float v0 = hrow[c0];
        const float v1 = has1 ? hrow[c1] : 0.f;
        acc0 = fmaf(pe, v0, acc0);
        acc1 = fmaf(pe, v1, acc1);
        d0 += pe;
    }
    float r0 = (end > beg) ? acc0 / d0 : 0.f;
    float r1 = (end > beg) ? acc1 / d0 : 0.f;
    outp[(size_t)n * 100 + c0] = r0 + bias[c0];
    if (has1) outp[(size_t)n * 100 + c1] = r1 + bias[c1];
}

extern "C" void kernel_launch(void* const* d_in, const int* in_sizes, int n_in,
                              void* d_out, int out_size, void* d_ws, size_t ws_size,
                              hipStream_t stream) {
    const float* x_A   = (const float*)d_in[0];
    const float* x_B   = (const float*)d_in[1];
    const int*   ei_AB = (const int*)d_in[2];
    const int*   ei_BA = (const int*)d_in[3];
    const float* w_AB  = (const float*)d_in[4];
    const float* w_BA  = (const float*)d_in[5];
    const float* l1AB_Ws = (const float*)d_in[6];
    const float* l1AB_Wd = (const float*)d_in[7];
    const float* l1AB_as = (const float*)d_in[8];
    const float* l1AB_ad = (const float*)d_in[9];
    const float* l1AB_We = (const float*)d_in[10];
    const float* l1AB_ae = (const float*)d_in[11];
    const float* l1AB_b  = (const float*)d_in[12];
    const float* l2AB_Ws = (const float*)d_in[13];
    const float* l2AB_Wd = (const float*)d_in[14];
    const float* l2AB_as = (const float*)d_in[15];
    const float* l2AB_ad = (const float*)d_in[16];
    const float* l2AB_b  = (const float*)d_in[17];
    const float* l1BA_Ws = (const float*)d_in[18];
    const float* l1BA_Wd = (const float*)d_in[19];
    const float* l1BA_as = (const float*)d_in[20];
    const float* l1BA_ad = (const float*)d_in[21];
    const float* l1BA_We = (const float*)d_in[22];
    const float* l1BA_ae = (const float*)d_in[23];
    const float* l1BA_b  = (const float*)d_in[24];
    const float* l2BA_Ws = (const float*)d_in[25];
    const float* l2BA_Wd = (const float*)d_in[26];
    const float* l2BA_as = (const float*)d_in[27];
    const float* l2BA_ad = (const float*)d_in[28];
    const float* l2BA_b  = (const float*)d_in[29];

    const int N = NNODES, E = NEDGES;

    // ---- workspace carve (4-byte elements, 64-element aligned) ----
    size_t o = 0;
    auto alloc = [&](size_t n) { size_t r = o; o += (n + 63) & ~(size_t)63; return r; };
    size_t cntA = alloc(N), cntB = alloc(N);
    size_t roA = alloc(N + 1), roB = alloc(N + 1);
    size_t curA = alloc(N), curB = alloc(N);
    size_t ssA = alloc(E), ssB = alloc(E);
    size_t swA = alloc(E), swB = alloc(E);
    size_t ce8 = alloc(8);
    size_t h1sA = alloc((size_t)N * 100), h1dB = alloc((size_t)N * 100);
    size_t h1sB = alloc((size_t)N * 100), h1dA = alloc((size_t)N * 100);
    size_t a1sA = alloc((size_t)N * 4), a1dB = alloc((size_t)N * 4);
    size_t a1sB = alloc((size_t)N * 4), a1dA = alloc((size_t)N * 4);
    size_t hA1 = alloc((size_t)N * 100), hB1 = alloc((size_t)N * 100);
    (void)ws_size;

    float* wsf = (float*)d_ws;
    int*   wsi = (int*)d_ws;

    // zero edge-count histograms (cntA..cntB contiguous span)
    hipMemsetAsync(wsi + cntA, 0, sizeof(int) * (cntB + N - cntA), stream);

    ce_kernel<<<2, 128, 0, stream>>>(l1AB_We, l1AB_ae, l1BA_We, l1BA_ae, wsf + ce8);

    const int eb = (2 * E + 255) / 256;
    count_kernel<<<eb, 256, 0, stream>>>(ei_AB, ei_BA, E, wsi + cntA, wsi + cntB);
    scan_kernel<<<2, 1024, 0, stream>>>(wsi + cntA, wsi + cntB, wsi + roA, wsi + roB,
                                        wsi + curA, wsi + curB, N);
    fill_kernel<<<eb, 256, 0, stream>>>(ei_AB, ei_BA, w_AB, w_BA, E, wsi + curA, wsi + curB,
                                        wsi + ssA, wsi + ssB, wsf + swA, wsf + swB);

    const int gb = N / 16;  // 3125
    // layer-1 node transforms
    gemm_att_kernel<128, 4><<<gb, 128, 0, stream>>>(x_A, l1AB_Ws, l1AB_as, wsf + h1sA, wsf + a1sA, N);
    gemm_att_kernel<128, 4><<<gb, 128, 0, stream>>>(x_B, l1AB_Wd, l1AB_ad, wsf + h1dB, wsf + a1dB, N);
    gemm_att_kernel<128, 4><<<gb, 128, 0, stream>>>(x_B, l1BA_Ws, l1BA_as, wsf + h1sB, wsf + a1sB, N);
    gemm_att_kernel<128, 4><<<gb, 128, 0, stream>>>(x_A, l1BA_Wd, l1BA_ad, wsf + h1dA, wsf + a1dA, N);

    const int wb = (N + 3) / 4;  // wave per node, 4 waves/block
    gather4_kernel<<<wb, 256, 0, stream>>>(wsi + roA, wsi + ssA, wsf + swA, wsf + h1sA,
                                           wsf + a1sA, wsf + a1dB, wsf + ce8, l1AB_b,
                                           wsf + hB1, N);
    gather4_kernel<<<wb, 256, 0, stream>>>(wsi + roB, wsi + ssB, wsf + swB, wsf + h1sB,
                                           wsf + a1sB, wsf + a1dA, wsf + ce8 + 4, l1BA_b,
                                           wsf + hA1, N);

    // layer-2 node transforms (reuse layer-1 buffers)
    gemm_att_kernel<100, 1><<<gb, 128, 0, stream>>>(wsf + hA1, l2AB_Ws, l2AB_as, wsf + h1sA, wsf + a1sA, N);
    gemm_att_kernel<100, 1><<<gb, 128, 0, stream>>>(wsf + hB1, l2AB_Wd, l2AB_ad, wsf + h1dB, wsf + a1dB, N);
    gemm_att_kernel<100, 1><<<gb, 128, 0, stream>>>(wsf + hB1, l2BA_Ws, l2BA_as, wsf + h1sB, wsf + a1sB, N);
    gemm_att_kernel<100, 1><<<gb, 128, 0, stream>>>(wsf + hA1, l2BA_Wd, l2BA_ad, wsf + h1dA, wsf + a1dA, N);

    float* out = (float*)d_out;
    // oB = AB direction (dst in B) -> d_out[5M..10M); oA = BA direction -> d_out[0..5M)
    gather1_kernel<<<wb, 256, 0, stream>>>(wsi + roA, wsi + ssA, wsf + h1sA, wsf + a1sA,
                                           wsf + a1dB, l2AB_b, out + (size_t)N * 100, N);
    gather1_kernel<<<wb, 256, 0, stream>>>(wsi + roB, wsi + ssB, wsf + h1sB, wsf + a1sB,
                                           wsf + a1dA, l2BA_b, out, N);
}